// Round 1
// baseline (452.304 us; speedup 1.0000x reference)
//
#include <hip/hip_runtime.h>
#include <stdint.h>

// DSN few-shot classifier, MI355X.
// out[q][w] = log_softmax_w( ||Uk_w^T q||^2 )   (query-norm cancels in softmax)
//
// ws layout:
//   [0,      4000)  G    : 5*10*10 double (Gram matrices)
//   [4096,   5896)  W    : 5*10*9 float   (V[:,k]/sigma_k, eigen-sorted desc)
//   [6144,   6344)  idx  : 5*10 int       (support indices per way)
//   [8192, 172032)  Upad : 80*1024 bf16   (way w -> rows 16w..16w+8; rest zero)
// total 172032 bytes required of ws.

typedef __attribute__((ext_vector_type(4))) float f32x4;
typedef __attribute__((ext_vector_type(8))) short s16x8;

#define WS_G_OFF    0
#define WS_W_OFF    4096
#define WS_IDX_OFF  6144
#define WS_U_OFF    8192

__device__ __forceinline__ unsigned short f2bf(float f) {
  unsigned int u = __float_as_uint(f);
  u += 0x7FFFu + ((u >> 16) & 1u);   // round-to-nearest-even
  return (unsigned short)(u >> 16);
}

// Detect whether labels buffer is int64 (viewed as int32 words) or int32.
// int64 one-hot: first 20 words = 2 rows; exactly one nonzero even word per
// row (2 total), all odd words zero. int32 data (4 rows in 20 words) fails.
__device__ __forceinline__ bool labels_int64(const int* L) {
  int cnt = 0; bool oddz = true;
  #pragma unroll
  for (int t = 0; t < 20; ++t) {
    int v = L[t];
    if (t & 1) { if (v) oddz = false; }
    else       { if (v) cnt++; }
  }
  return oddz && (cnt == 2);
}

__device__ __forceinline__ int cls_of(const int* L, bool is64, int i) {
  int best = -0x7fffffff, c = 0;
  #pragma unroll
  for (int j = 0; j < 5; ++j) {
    int v = is64 ? L[i * 10 + 2 * j] : L[i * 5 + j];
    if (v > best) { best = v; c = j; }
  }
  return c;
}

// ---------------- Kernel A1: Gram matrices, one wave per (w,a,b) pair -------
__global__ void dsn_gram(const float* __restrict__ support,
                         const int* __restrict__ labels,
                         double* __restrict__ G) {
  int wid  = blockIdx.x * 4 + (threadIdx.x >> 6);
  int lane = threadIdx.x & 63;
  if (wid >= 275) return;               // 5 ways * 55 upper-tri pairs
  int w = wid / 55, p = wid % 55;
  int a = 0;
  while (p >= 10 - a) { p -= 10 - a; a++; }
  int b = a + p;                        // a <= b

  bool is64 = labels_int64(labels);
  int myc = (lane < 50) ? cls_of(labels, is64, lane) : -1;
  unsigned long long mask = __ballot(lane < 50 && myc == w);

  unsigned long long m = mask;
  for (int i = 0; i < a; ++i) m &= m - 1;
  int ia = __ffsll((unsigned long long)m) - 1;
  m = mask;
  for (int i = 0; i < b; ++i) m &= m - 1;
  int ib = __ffsll((unsigned long long)m) - 1;

  const float* A = support + ia * 1024;
  const float* B = support + ib * 1024;
  double acc = 0.0;
  #pragma unroll
  for (int i = 0; i < 16; ++i) {
    int d = lane + 64 * i;
    acc += (double)A[d] * (double)B[d];
  }
  #pragma unroll
  for (int off = 32; off > 0; off >>= 1) acc += __shfl_xor(acc, off);
  if (lane == 0) {
    G[(w * 10 + a) * 10 + b] = acc;
    G[(w * 10 + b) * 10 + a] = acc;
  }
}

// ---------------- Kernel A2: Jacobi eigensolve (fp64), 1 block -------------
__global__ void dsn_eig(const int* __restrict__ labels,
                        const double* __restrict__ G,
                        float* __restrict__ W,
                        int* __restrict__ idx) {
  __shared__ int cls[50];
  __shared__ double Gw[5][10][10];
  __shared__ double Vw[5][10][10];
  int t = threadIdx.x;
  bool is64 = labels_int64(labels);
  if (t < 50) cls[t] = cls_of(labels, is64, t);
  __syncthreads();
  if (t < 5) {
    int w = t, s = 0;
    for (int i = 0; i < 50; ++i)
      if (cls[i] == w) { idx[w * 10 + s] = i; s++; }
    for (int i = 0; i < 10; ++i)
      for (int j = 0; j < 10; ++j) {
        Gw[w][i][j] = G[(w * 10 + i) * 10 + j];
        Vw[w][i][j] = (i == j) ? 1.0 : 0.0;
      }
    for (int sweep = 0; sweep < 16; ++sweep) {
      double off = 0;
      for (int i = 0; i < 10; ++i)
        for (int j = i + 1; j < 10; ++j) off += Gw[w][i][j] * Gw[w][i][j];
      if (off < 1e-16) break;
      for (int p = 0; p < 9; ++p)
        for (int q = p + 1; q < 10; ++q) {
          double apq = Gw[w][p][q];
          if (fabs(apq) < 1e-300) continue;
          double app = Gw[w][p][p], aqq = Gw[w][q][q];
          double th = (aqq - app) / (2.0 * apq);
          double tt = (th >= 0 ? 1.0 : -1.0) / (fabs(th) + sqrt(th * th + 1.0));
          double c = 1.0 / sqrt(tt * tt + 1.0), sn = tt * c;
          for (int i = 0; i < 10; ++i) {
            double gp = Gw[w][i][p], gq = Gw[w][i][q];
            Gw[w][i][p] = c * gp - sn * gq;
            Gw[w][i][q] = sn * gp + c * gq;
          }
          for (int i = 0; i < 10; ++i) {
            double gp = Gw[w][p][i], gq = Gw[w][q][i];
            Gw[w][p][i] = c * gp - sn * gq;
            Gw[w][q][i] = sn * gp + c * gq;
          }
          for (int i = 0; i < 10; ++i) {
            double vp = Vw[w][i][p], vq = Vw[w][i][q];
            Vw[w][i][p] = c * vp - sn * vq;
            Vw[w][i][q] = sn * vp + c * vq;
          }
        }
    }
    double ev[10]; int ord[10];
    for (int i = 0; i < 10; ++i) { ev[i] = Gw[w][i][i]; ord[i] = i; }
    for (int i = 0; i < 9; ++i) {
      int mx = i;
      for (int j = i + 1; j < 10; ++j)
        if (ev[ord[j]] > ev[ord[mx]]) mx = j;
      int tmp = ord[i]; ord[i] = ord[mx]; ord[mx] = tmp;
    }
    for (int k = 0; k < 9; ++k) {
      double lam = ev[ord[k]];
      double inv = (lam > 0.0) ? 1.0 / sqrt(lam) : 0.0;
      for (int s2 = 0; s2 < 10; ++s2)
        W[(w * 10 + s2) * 9 + k] = (float)(Vw[w][s2][ord[k]] * inv);
    }
  }
}

// ---------------- Kernel A3: materialize Upad (80 x 1024 bf16) -------------
__global__ void dsn_basis(const float* __restrict__ support,
                          const float* __restrict__ W,
                          const int* __restrict__ idx,
                          unsigned short* __restrict__ U) {
  int r = blockIdx.x;              // 0..79
  int w = r >> 4, kk = r & 15;
  unsigned short* Urow = U + r * 1024;
  if (kk >= 9) {
    for (int d = threadIdx.x; d < 1024; d += 256) Urow[d] = 0;
    return;
  }
  float wv[10]; int id[10];
  #pragma unroll
  for (int s = 0; s < 10; ++s) {
    wv[s] = W[(w * 10 + s) * 9 + kk];
    id[s] = idx[w * 10 + s];
  }
  for (int d = threadIdx.x; d < 1024; d += 256) {
    float sum = 0.f;
    #pragma unroll
    for (int s = 0; s < 10; ++s) sum += support[id[s] * 1024 + d] * wv[s];
    Urow[d] = f2bf(sum);
  }
}

// ---------------- Kernel B: main — MFMA coeffs + log_softmax ---------------
// 16 queries per wave. A = Upad (5 row-tiles, one per way), B = Q^T fragment.
// D[row=channel][col=query]: col = lane&15, row = (lane>>4)*4 + reg  (m89).
__global__ __launch_bounds__(256) void dsn_main(const float* __restrict__ query,
                                                const unsigned short* __restrict__ U,
                                                float* __restrict__ out) {
  int wid  = blockIdx.x * 4 + (threadIdx.x >> 6);
  int lane = threadIdx.x & 63;
  int q0   = wid * 16;
  int qrow = lane & 15;
  int kbase = (lane >> 4) * 8;

  const float* qp = query + (size_t)(q0 + qrow) * 1024 + kbase;
  const unsigned short* up = U + qrow * 1024 + kbase;

  f32x4 acc[5];
  #pragma unroll
  for (int w = 0; w < 5; ++w) acc[w] = (f32x4){0.f, 0.f, 0.f, 0.f};

  #pragma unroll 4
  for (int kt = 0; kt < 32; ++kt) {
    const float* qk = qp + kt * 32;
    f32x4 lo = *(const f32x4*)qk;
    f32x4 hi = *(const f32x4*)(qk + 4);
    s16x8 bf;
    bf[0] = (short)f2bf(lo[0]); bf[1] = (short)f2bf(lo[1]);
    bf[2] = (short)f2bf(lo[2]); bf[3] = (short)f2bf(lo[3]);
    bf[4] = (short)f2bf(hi[0]); bf[5] = (short)f2bf(hi[1]);
    bf[6] = (short)f2bf(hi[2]); bf[7] = (short)f2bf(hi[3]);
    const unsigned short* uk = up + kt * 32;
    #pragma unroll
    for (int w = 0; w < 5; ++w) {
      s16x8 av = *(const s16x8*)(uk + w * 16384);   // row w*16 + qrow
      acc[w] = __builtin_amdgcn_mfma_f32_16x16x32_bf16(av, bf, acc[w], 0, 0, 0);
    }
  }

  // s_w = sum over 16 channel-rows of coeff^2 (rows 9..15 are zero-padded)
  float sv[5];
  #pragma unroll
  for (int w = 0; w < 5; ++w) {
    float tcc = acc[w][0] * acc[w][0] + acc[w][1] * acc[w][1] +
                acc[w][2] * acc[w][2] + acc[w][3] * acc[w][3];
    tcc += __shfl_xor(tcc, 16);
    tcc += __shfl_xor(tcc, 32);
    sv[w] = tcc;
  }
  float mx = fmaxf(fmaxf(fmaxf(sv[0], sv[1]), fmaxf(sv[2], sv[3])), sv[4]);
  float sum = 0.f;
  #pragma unroll
  for (int w = 0; w < 5; ++w) sum += expf(sv[w] - mx);
  float lse = mx + logf(sum);
  if (lane < 16) {
    float* o = out + (size_t)(q0 + lane) * 5;
    #pragma unroll
    for (int w = 0; w < 5; ++w) o[w] = sv[w] - lse;
  }
}

extern "C" void kernel_launch(void* const* d_in, const int* in_sizes, int n_in,
                              void* d_out, int out_size, void* d_ws, size_t ws_size,
                              hipStream_t stream) {
  const float* support = (const float*)d_in[0];
  const int*   labels  = (const int*)d_in[1];
  const float* query   = (const float*)d_in[2];
  float* out = (float*)d_out;
  char* ws = (char*)d_ws;

  double*         G   = (double*)(ws + WS_G_OFF);
  float*          W   = (float*)(ws + WS_W_OFF);
  int*            idx = (int*)(ws + WS_IDX_OFF);
  unsigned short* U   = (unsigned short*)(ws + WS_U_OFF);

  int nq = in_sizes[2] / 1024;          // 16384
  int nwaves = nq / 16;                 // 1024
  int nblocks = (nwaves + 3) / 4;       // 256

  hipLaunchKernelGGL(dsn_gram,  dim3(69), dim3(256), 0, stream, support, labels, G);
  hipLaunchKernelGGL(dsn_eig,   dim3(1),  dim3(64),  0, stream, labels, G, W, idx);
  hipLaunchKernelGGL(dsn_basis, dim3(80), dim3(256), 0, stream, support, W, idx, U);
  hipLaunchKernelGGL(dsn_main,  dim3(nblocks), dim3(256), 0, stream, query, U, out);
}

// Round 2
// 76.706 us; speedup vs baseline: 5.8966x; 5.8966x over previous
//
#include <hip/hip_runtime.h>
#include <stdint.h>

// DSN few-shot classifier, MI355X.
// out[q][w] = log_softmax_w( ||P9_w q||^2 ),  query-norm cancels in softmax.
// P9 = P_colspace - u_min u_min^T, so s_w = ||B^T q||^2 - (u_min . q)^2 with
// B = M L^{-T} (G = L L^T Cholesky) an exact ONB of colspace(M).
//
// ws layout:
//   [0,      4000)  G    : 5*10*10 double (Gram matrices, full storage)
//   [4096,   6296)  W    : 5*11*10 float  (rows 0..9: L^{-T} cols; row 10: v_min/|Mv|)
//   [6400,   6600)  idx  : 5*10 int       (support indices per way)
//   [8192, 172032)  Upad : 80*1024 bf16   (way w -> rows 16w..16w+10; rest zero)

typedef __attribute__((ext_vector_type(4))) float f32x4;
typedef __attribute__((ext_vector_type(8))) short s16x8;

#define WS_G_OFF    0
#define WS_W_OFF    4096
#define WS_IDX_OFF  6400
#define WS_U_OFF    8192

__device__ __forceinline__ unsigned short f2bf(float f) {
  unsigned int u = __float_as_uint(f);
  u += 0x7FFFu + ((u >> 16) & 1u);   // round-to-nearest-even
  return (unsigned short)(u >> 16);
}

__device__ __forceinline__ constexpr int PU(int i, int j) {  // upper packed, i<=j
  return 10 * i - i * (i - 1) / 2 + (j - i);
}
__device__ __forceinline__ constexpr int PL(int i, int j) {  // strict lower, i>j
  return i * (i - 1) / 2 + j;
}
__device__ __forceinline__ constexpr int CI(int i, int j) {  // lower incl diag, i>=j
  return i * (i + 1) / 2 + j;
}

// int64 vs int32 one-hot labels detection (validated R0).
__device__ __forceinline__ bool labels_int64(const int* L) {
  int cnt = 0; bool oddz = true;
  #pragma unroll
  for (int t = 0; t < 20; ++t) {
    int v = L[t];
    if (t & 1) { if (v) oddz = false; }
    else       { if (v) cnt++; }
  }
  return oddz && (cnt == 2);
}

__device__ __forceinline__ int cls_of(const int* L, bool is64, int i) {
  int best = -0x7fffffff, c = 0;
  #pragma unroll
  for (int j = 0; j < 5; ++j) {
    int v = is64 ? L[i * 10 + 2 * j] : L[i * 5 + j];
    if (v > best) { best = v; c = j; }
  }
  return c;
}

// ---------------- Kernel A1: Gram matrices, one wave per (w,a,b) pair -------
__global__ void dsn_gram(const float* __restrict__ support,
                         const int* __restrict__ labels,
                         double* __restrict__ G) {
  int wid  = blockIdx.x * 4 + (threadIdx.x >> 6);
  int lane = threadIdx.x & 63;
  if (wid >= 275) return;               // 5 ways * 55 upper-tri pairs
  int w = wid / 55, p = wid % 55;
  int a = 0;
  while (p >= 10 - a) { p -= 10 - a; a++; }
  int b = a + p;                        // a <= b

  bool is64 = labels_int64(labels);
  int myc = (lane < 50) ? cls_of(labels, is64, lane) : -1;
  unsigned long long mask = __ballot(lane < 50 && myc == w);

  unsigned long long m = mask;
  for (int i = 0; i < a; ++i) m &= m - 1;
  int ia = __ffsll((unsigned long long)m) - 1;
  m = mask;
  for (int i = 0; i < b; ++i) m &= m - 1;
  int ib = __ffsll((unsigned long long)m) - 1;

  const float* A = support + ia * 1024;
  const float* B = support + ib * 1024;
  double acc = 0.0;
  #pragma unroll
  for (int i = 0; i < 16; ++i) {
    int d = lane + 64 * i;
    acc += (double)A[d] * (double)B[d];
  }
  #pragma unroll
  for (int off = 32; off > 0; off >>= 1) acc += __shfl_xor(acc, off);
  if (lane == 0) {
    G[(w * 10 + a) * 10 + b] = acc;
    G[(w * 10 + b) * 10 + a] = acc;
  }
}

// ---------------- register-resident 10x10 fp64 linear algebra ---------------
// LDL^T of (G - sigma I); returns count of negative pivots (Sylvester inertia).
__device__ __forceinline__ int ldl10(const double (&g)[55], double sigma,
                                     double (&Lw)[45], double (&d)[10]) {
  int neg = 0;
  #pragma unroll
  for (int j = 0; j < 10; ++j) {
    double s = g[PU(j, j)] - sigma;
    #pragma unroll
    for (int k = 0; k < j; ++k) s -= Lw[PL(j, k)] * Lw[PL(j, k)] * d[k];
    d[j] = s;
    if (s < 0.0) neg++;
    double inv = 1.0 / s;
    #pragma unroll
    for (int i = j + 1; i < 10; ++i) {
      double t = g[PU(j, i)];
      #pragma unroll
      for (int k = 0; k < j; ++k) t -= Lw[PL(i, k)] * Lw[PL(j, k)] * d[k];
      Lw[PL(i, j)] = t * inv;
    }
  }
  return neg;
}

// solve (L D L^T) x = x in place (L unit strict-lower packed).
__device__ __forceinline__ void ldlsolve10(const double (&Lw)[45],
                                           const double (&d)[10],
                                           double (&x)[10]) {
  #pragma unroll
  for (int i = 1; i < 10; ++i) {
    #pragma unroll
    for (int j = 0; j < i; ++j) x[i] -= Lw[PL(i, j)] * x[j];
  }
  #pragma unroll
  for (int i = 0; i < 10; ++i) x[i] *= (1.0 / d[i]);
  #pragma unroll
  for (int i = 8; i >= 0; --i) {
    #pragma unroll
    for (int j = i + 1; j < 10; ++j) x[i] -= Lw[PL(j, i)] * x[j];
  }
}

// ---------------- Kernel A2: per-way subspace (5 lanes, all registers) ------
__global__ __launch_bounds__(64, 1) void dsn_eig(const int* __restrict__ labels,
                                                 const double* __restrict__ G,
                                                 float* __restrict__ W,
                                                 int* __restrict__ idx) {
  __shared__ int cls[50];
  int t = threadIdx.x;
  bool is64 = labels_int64(labels);
  if (t < 50) cls[t] = cls_of(labels, is64, t);
  __syncthreads();
  if (t >= 5) return;
  int w = t, scnt = 0;
  for (int i = 0; i < 50; ++i)
    if (cls[i] == w) { idx[w * 10 + scnt] = i; scnt++; }

  // load Gram (upper packed) into registers
  double gg[55];
  #pragma unroll
  for (int i = 0; i < 10; ++i)
    #pragma unroll
    for (int j = i; j < 10; ++j)
      gg[PU(i, j)] = G[(w * 10 + i) * 10 + j];

  // Gershgorin bracket for lambda_min
  double lo = 1e300, hi = 1e300;
  #pragma unroll
  for (int i = 0; i < 10; ++i) {
    double r = 0.0, di = gg[PU(i, i)];
    #pragma unroll
    for (int j = 0; j < 10; ++j) {
      if (j == i) continue;
      double v = (j < i) ? gg[PU(j, i)] : gg[PU(i, j)];
      r += fabs(v);
    }
    lo = fmin(lo, di - r);
    hi = fmin(hi, di);
  }
  lo = fmax(lo, 0.0);
  hi = hi * (1.0 + 1e-9) + 1e-12;

  double Lw[45], d[10];
  // bisection on inertia: after loop count(lo)==0, count(hi)>=1
  #pragma unroll 1
  for (int it = 0; it < 12; ++it) {
    double mid = 0.5 * (lo + hi);
    int neg = ldl10(gg, mid, Lw, d);
    if (neg == 0) lo = mid; else hi = mid;
  }
  double sigma = lo - (hi - lo) - 1e-6;   // strictly below lambda_min

  // inverse iteration (2 solves) for v_min
  ldl10(gg, sigma, Lw, d);
  double x[10];
  #pragma unroll
  for (int i = 0; i < 10; ++i) x[i] = 1.0;
  ldlsolve10(Lw, d, x);
  double mx = 0.0;
  #pragma unroll
  for (int i = 0; i < 10; ++i) mx = fmax(mx, fabs(x[i]));
  double rmx = 1.0 / mx;
  #pragma unroll
  for (int i = 0; i < 10; ++i) x[i] *= rmx;
  ldlsolve10(Lw, d, x);

  // row 10 coefficients: v / ||M v||, ||M v||^2 = v^T G v
  double denom = 0.0;
  #pragma unroll
  for (int i = 0; i < 10; ++i) {
    double gv = 0.0;
    #pragma unroll
    for (int j = 0; j < 10; ++j) {
      double v = (j < i) ? gg[PU(j, i)] : gg[PU(i, j)];
      gv += v * x[j];
    }
    denom += x[i] * gv;
  }
  double sc = 1.0 / sqrt(denom);
  #pragma unroll
  for (int s = 0; s < 10; ++s)
    W[(w * 11 + 10) * 10 + s] = (float)(x[s] * sc);

  // Cholesky G = Lc Lc^T (lower incl diag, packed)
  double Lc[55];
  #pragma unroll
  for (int j = 0; j < 10; ++j) {
    double s = gg[PU(j, j)];
    #pragma unroll
    for (int k = 0; k < j; ++k) s -= Lc[CI(j, k)] * Lc[CI(j, k)];
    double dj = sqrt(s);
    Lc[CI(j, j)] = dj;
    double inv = 1.0 / dj;
    #pragma unroll
    for (int i = j + 1; i < 10; ++i) {
      double tt = gg[PU(j, i)];
      #pragma unroll
      for (int k = 0; k < j; ++k) tt -= Lc[CI(i, k)] * Lc[CI(j, k)];
      Lc[CI(i, j)] = tt * inv;
    }
  }

  // rows 0..9: column r of L^{-T}  (solve L^T c = e_r, back-substitution)
  #pragma unroll 1
  for (int r = 0; r < 10; ++r) {
    double c[10];
    #pragma unroll
    for (int s = 9; s >= 0; --s) {
      double tt = (s == r) ? 1.0 : 0.0;
      #pragma unroll
      for (int u = s + 1; u < 10; ++u) tt -= Lc[CI(u, s)] * c[u];
      c[s] = tt / Lc[CI(s, s)];
    }
    #pragma unroll
    for (int s = 0; s < 10; ++s)
      W[(w * 11 + r) * 10 + s] = (float)c[s];
  }
}

// ---------------- Kernel A3: materialize Upad (80 x 1024 bf16) -------------
__global__ void dsn_basis(const float* __restrict__ support,
                          const float* __restrict__ W,
                          const int* __restrict__ idx,
                          unsigned short* __restrict__ U) {
  int r = blockIdx.x;              // 0..79
  int w = r >> 4, kk = r & 15;
  unsigned short* Urow = U + r * 1024;
  if (kk >= 11) {
    for (int d = threadIdx.x; d < 1024; d += 256) Urow[d] = 0;
    return;
  }
  float wv[10]; int id[10];
  #pragma unroll
  for (int s = 0; s < 10; ++s) {
    wv[s] = W[(w * 11 + kk) * 10 + s];
    id[s] = idx[w * 10 + s];
  }
  for (int d = threadIdx.x; d < 1024; d += 256) {
    float sum = 0.f;
    #pragma unroll
    for (int s = 0; s < 10; ++s) sum += support[id[s] * 1024 + d] * wv[s];
    Urow[d] = f2bf(sum);
  }
}

// ---------------- Kernel B: main — MFMA coeffs + log_softmax ---------------
// 16 queries per wave. A = Upad (5 row-tiles, one per way), B = Q^T fragment.
// D[row=channel][col=query]: col = lane&15, row = (lane>>4)*4 + reg  (m89).
// Row 10 (u_min) lives at lane-group 2, reg 2 -> its square is SUBTRACTED.
__global__ __launch_bounds__(256) void dsn_main(const float* __restrict__ query,
                                                const unsigned short* __restrict__ U,
                                                float* __restrict__ out) {
  int wid  = blockIdx.x * 4 + (threadIdx.x >> 6);
  int lane = threadIdx.x & 63;
  int q0   = wid * 16;
  int qrow = lane & 15;
  int kbase = (lane >> 4) * 8;

  const float* qp = query + (size_t)(q0 + qrow) * 1024 + kbase;
  const unsigned short* up = U + qrow * 1024 + kbase;

  f32x4 acc[5];
  #pragma unroll
  for (int w = 0; w < 5; ++w) acc[w] = (f32x4){0.f, 0.f, 0.f, 0.f};

  #pragma unroll 4
  for (int kt = 0; kt < 32; ++kt) {
    const float* qk = qp + kt * 32;
    f32x4 lo = *(const f32x4*)qk;
    f32x4 hi = *(const f32x4*)(qk + 4);
    s16x8 bf;
    bf[0] = (short)f2bf(lo[0]); bf[1] = (short)f2bf(lo[1]);
    bf[2] = (short)f2bf(lo[2]); bf[3] = (short)f2bf(lo[3]);
    bf[4] = (short)f2bf(hi[0]); bf[5] = (short)f2bf(hi[1]);
    bf[6] = (short)f2bf(hi[2]); bf[7] = (short)f2bf(hi[3]);
    const unsigned short* uk = up + kt * 32;
    #pragma unroll
    for (int w = 0; w < 5; ++w) {
      s16x8 av = *(const s16x8*)(uk + w * 16384);   // row w*16 + qrow
      acc[w] = __builtin_amdgcn_mfma_f32_16x16x32_bf16(av, bf, acc[w], 0, 0, 0);
    }
  }

  // s_w = sum_{rows 0..9} c^2 - c_10^2 (rows 11..15 zero-padded)
  float sgn2 = ((lane >> 4) == 2) ? -1.f : 1.f;   // reg 2 of group 2 = row 10
  float sv[5];
  #pragma unroll
  for (int w = 0; w < 5; ++w) {
    float tcc = acc[w][0] * acc[w][0] + acc[w][1] * acc[w][1] +
                sgn2 * acc[w][2] * acc[w][2] + acc[w][3] * acc[w][3];
    tcc += __shfl_xor(tcc, 16);
    tcc += __shfl_xor(tcc, 32);
    sv[w] = tcc;
  }
  float mx = fmaxf(fmaxf(fmaxf(sv[0], sv[1]), fmaxf(sv[2], sv[3])), sv[4]);
  float sum = 0.f;
  #pragma unroll
  for (int w = 0; w < 5; ++w) sum += expf(sv[w] - mx);
  float lse = mx + logf(sum);
  if (lane < 16) {
    float* o = out + (size_t)(q0 + lane) * 5;
    #pragma unroll
    for (int w = 0; w < 5; ++w) o[w] = sv[w] - lse;
  }
}

extern "C" void kernel_launch(void* const* d_in, const int* in_sizes, int n_in,
                              void* d_out, int out_size, void* d_ws, size_t ws_size,
                              hipStream_t stream) {
  const float* support = (const float*)d_in[0];
  const int*   labels  = (const int*)d_in[1];
  const float* query   = (const float*)d_in[2];
  float* out = (float*)d_out;
  char* ws = (char*)d_ws;

  double*         G   = (double*)(ws + WS_G_OFF);
  float*          W   = (float*)(ws + WS_W_OFF);
  int*            idx = (int*)(ws + WS_IDX_OFF);
  unsigned short* U   = (unsigned short*)(ws + WS_U_OFF);

  int nq = in_sizes[2] / 1024;          // 16384
  int nwaves = nq / 16;                 // 1024
  int nblocks = (nwaves + 3) / 4;       // 256

  hipLaunchKernelGGL(dsn_gram,  dim3(69), dim3(256), 0, stream, support, labels, G);
  hipLaunchKernelGGL(dsn_eig,   dim3(1),  dim3(64),  0, stream, labels, G, W, idx);
  hipLaunchKernelGGL(dsn_basis, dim3(80), dim3(256), 0, stream, support, W, idx, U);
  hipLaunchKernelGGL(dsn_main,  dim3(nblocks), dim3(256), 0, stream, query, U, out);
}